// Round 7
// baseline (98.406 us; speedup 1.0000x reference)
//
#include <hip/hip_runtime.h>
#include <float.h>

// Chamfer L2, B=4, N=M=8192 fp32 -> scalar.
// d(q,p) = |q|^2 + |p|^2 - 2 q.p ; track s = q.p - 0.5|p|^2, min d = |q|^2 - 2 max s.
//
// R7: LDS-pipe was the R5/R6 limiter (4x ds_read_b128/iter ~= 41us/CU model).
//  - QPT=8: each LDS point feeds 8 queries -> LDS instr/pair halved.
//  - packed accumulators via v_pk_max_f32: no per-iter unpack movs.
//  - NCH=32 (CHUNK=256, 4KB LDS), GRID=1024 -> 4 blocks/CU.
// Inner loop per 2 points per query: 3 v_pk_fma_f32 + 1 v_pk_max_f32.

typedef float v2f __attribute__((ext_vector_type(2)));
typedef float v4f __attribute__((ext_vector_type(4)));

#define BLK   256
#define QPT   8
#define QPB   (BLK * QPT)        // 2048 queries per block
#define BATCH 4
#define NPTS  8192
#define NCH   32
#define CHUNK (NPTS / NCH)       // 256 points staged (4 KB LDS)
#define QTILES (NPTS / QPB)      // 4
#define GRID  (2 * BATCH * QTILES * NCH)  // 1024
#define TOTQ  (2 * BATCH * NPTS)          // 65536

__global__ __launch_bounds__(BLK) void init_kernel(unsigned* mins, float* out, int n) {
    int i = blockIdx.x * BLK + threadIdx.x;
    if (i < n) mins[i] = 0x7F7FFFFFu;  // FLT_MAX bit pattern
    if (i == 0) out[0] = 0.f;
}

__global__ __launch_bounds__(BLK) void cd_chunk_kernel(
    const float* __restrict__ p1, const float* __restrict__ p2,
    unsigned* __restrict__ mins)
{
    __shared__ v4f pts[CHUNK];   // CHUNK/2 pair-entries x 2 v4f:
                                 //   {x0,x1,y0,y1} {z0,z1,w0,w1}
    int bid    = blockIdx.x;
    int mchunk = bid & (NCH - 1);
    int qt     = (bid >> 5) & (QTILES - 1);
    int batch  = (bid >> 7) & (BATCH - 1);
    int dir    = bid >> 9;

    const float* qbase = (dir == 0 ? p1 : p2) + (size_t)batch * NPTS * 3;
    const float* dbase = (dir == 0 ? p2 : p1) + (size_t)batch * NPTS * 3;

    int tid = threadIdx.x;

    // ---- stage 256 points as 128 SoA pair-entries (threads 0..63) ----
    if (tid < CHUNK / 4) {
        int t4 = tid * 4;
        const float* s = dbase + (size_t)(mchunk * CHUNK + t4) * 3;
        float4 f0 = *(const float4*)(s);
        float4 f1 = *(const float4*)(s + 4);
        float4 f2 = *(const float4*)(s + 8);
        float x0 = f0.x, y0 = f0.y, z0 = f0.z;
        float x1 = f0.w, y1 = f1.x, z1 = f1.y;
        float x2 = f1.z, y2 = f1.w, z2 = f2.x;
        float x3 = f2.y, y3 = f2.z, z3 = f2.w;
        float w0 = -0.5f * (x0*x0 + y0*y0 + z0*z0);
        float w1 = -0.5f * (x1*x1 + y1*y1 + z1*z1);
        float w2 = -0.5f * (x2*x2 + y2*y2 + z2*z2);
        float w3 = -0.5f * (x3*x3 + y3*y3 + z3*z3);
        pts[4*tid + 0] = (v4f){x0, x1, y0, y1};
        pts[4*tid + 1] = (v4f){z0, z1, w0, w1};
        pts[4*tid + 2] = (v4f){x2, x3, y2, y3};
        pts[4*tid + 3] = (v4f){z2, z3, w2, w3};
    }

    v2f qx2[QPT], qy2[QPT], qz2[QPT];
    float qn[QPT];
    #pragma unroll
    for (int k = 0; k < QPT; ++k) {
        int q = qt * QPB + k * BLK + tid;
        const float* s = qbase + (size_t)q * 3;
        float qx = s[0], qy = s[1], qz = s[2];
        qx2[k] = (v2f){qx, qx};
        qy2[k] = (v2f){qy, qy};
        qz2[k] = (v2f){qz, qz};
        qn[k] = qx * qx + qy * qy + qz * qz;
    }
    __syncthreads();

    v2f acc0[QPT], acc1[QPT];
    #pragma unroll
    for (int k = 0; k < QPT; ++k) {
        acc0[k] = (v2f){-FLT_MAX, -FLT_MAX};
        acc1[k] = (v2f){-FLT_MAX, -FLT_MAX};
    }

    // ---- scan: 2 pair-entries (4 points) per iteration, 8 queries each ----
    #pragma unroll 2
    for (int m = 0; m < CHUNK / 2; m += 2) {
        v4f u0 = pts[2*m + 0];   // x0 x1 y0 y1
        v4f v0 = pts[2*m + 1];   // z0 z1 w0 w1
        v4f u1 = pts[2*m + 2];
        v4f v1 = pts[2*m + 3];
        v2f X0 = __builtin_shufflevector(u0, u0, 0, 1);
        v2f Y0 = __builtin_shufflevector(u0, u0, 2, 3);
        v2f Z0 = __builtin_shufflevector(v0, v0, 0, 1);
        v2f W0 = __builtin_shufflevector(v0, v0, 2, 3);
        v2f X1 = __builtin_shufflevector(u1, u1, 0, 1);
        v2f Y1 = __builtin_shufflevector(u1, u1, 2, 3);
        v2f Z1 = __builtin_shufflevector(v1, v1, 0, 1);
        v2f W1 = __builtin_shufflevector(v1, v1, 2, 3);
        #pragma unroll
        for (int k = 0; k < QPT; ++k) {
            v2f s0 = __builtin_elementwise_fma(qz2[k], Z0,
                      __builtin_elementwise_fma(qy2[k], Y0,
                       __builtin_elementwise_fma(qx2[k], X0, W0)));
            acc0[k] = __builtin_elementwise_max(acc0[k], s0);   // v_pk_max_f32
            v2f s1 = __builtin_elementwise_fma(qz2[k], Z1,
                      __builtin_elementwise_fma(qy2[k], Y1,
                       __builtin_elementwise_fma(qx2[k], X1, W1)));
            acc1[k] = __builtin_elementwise_max(acc1[k], s1);
        }
    }

    unsigned qid = (unsigned)(dir * (BATCH * NPTS) + batch * NPTS + qt * QPB + tid);
    #pragma unroll
    for (int k = 0; k < QPT; ++k) {
        float mx = fmaxf(fmaxf(acc0[k].x, acc0[k].y), fmaxf(acc1[k].x, acc1[k].y));
        float d = fmaxf(qn[k] - 2.f * mx, 0.f);
        atomicMin(&mins[qid + k * BLK], __float_as_uint(d));
    }
}

__global__ __launch_bounds__(BLK) void sum_kernel(
    const unsigned* __restrict__ mins, float* __restrict__ out, int n, float scale)
{
    int i = blockIdx.x * BLK + threadIdx.x;
    int stride = gridDim.x * BLK;
    float v = 0.f;
    for (int idx = i; idx < n; idx += stride) v += __uint_as_float(mins[idx]);
    for (int off = 32; off > 0; off >>= 1) v += __shfl_down(v, off, 64);
    __shared__ float wsum[BLK / 64];
    int lane = threadIdx.x & 63, wid = threadIdx.x >> 6;
    if (lane == 0) wsum[wid] = v;
    __syncthreads();
    if (threadIdx.x == 0) {
        float t = 0.f;
        for (int w = 0; w < BLK / 64; ++w) t += wsum[w];
        atomicAdd(out, t * scale);
    }
}

__global__ void zero_out_kernel(float* out) { out[0] = 0.f; }

// Fallback (ws too small): single-kernel whole-DB scan.
__global__ __launch_bounds__(BLK) void cd_full_kernel(
    const float* __restrict__ p1, const float* __restrict__ p2,
    float* __restrict__ out)
{
    __shared__ float4 pts[2048];
    int bid   = blockIdx.x;       // 0..127
    int qt    = bid & 15;
    int batch = (bid >> 4) & 3;
    int dir   = bid >> 6;

    const float* qbase = (dir == 0 ? p1 : p2) + (size_t)batch * NPTS * 3;
    const float* dbase = (dir == 0 ? p2 : p1) + (size_t)batch * NPTS * 3;

    int tid = threadIdx.x;
    int q0 = qt * 512 + tid;
    int q1 = q0 + BLK;
    float ax = qbase[q0 * 3 + 0], ay = qbase[q0 * 3 + 1], az = qbase[q0 * 3 + 2];
    float bx = qbase[q1 * 3 + 0], by = qbase[q1 * 3 + 1], bz = qbase[q1 * 3 + 2];
    float an = ax * ax + ay * ay + az * az;
    float bn = bx * bx + by * by + bz * bz;

    float sa = -FLT_MAX, sb = -FLT_MAX;
    for (int c = 0; c < 4; ++c) {
        __syncthreads();
        int mstart = c * 2048;
        for (int j = tid; j < 2048; j += BLK) {
            const float* s = dbase + (size_t)(mstart + j) * 3;
            float x = s[0], y = s[1], z = s[2];
            pts[j] = make_float4(x, y, z, -0.5f * (x * x + y * y + z * z));
        }
        __syncthreads();
        #pragma unroll 4
        for (int j = 0; j < 2048; j += 2) {
            float4 u = pts[j];
            float4 v = pts[j + 1];
            float s;
            s = fmaf(ax, u.x, u.w); s = fmaf(ay, u.y, s); s = fmaf(az, u.z, s); sa = fmaxf(sa, s);
            s = fmaf(bx, u.x, u.w); s = fmaf(by, u.y, s); s = fmaf(bz, u.z, s); sb = fmaxf(sb, s);
            s = fmaf(ax, v.x, v.w); s = fmaf(ay, v.y, s); s = fmaf(az, v.z, s); sa = fmaxf(sa, s);
            s = fmaf(bx, v.x, v.w); s = fmaf(by, v.y, s); s = fmaf(bz, v.z, s); sb = fmaxf(sb, s);
        }
    }
    float da = fmaxf(an - 2.f * sa, 0.f);
    float db = fmaxf(bn - 2.f * sb, 0.f);
    float v = da + db;
    for (int off = 32; off > 0; off >>= 1) v += __shfl_down(v, off, 64);
    __shared__ float wsum[BLK / 64];
    int lane = threadIdx.x & 63, wid = threadIdx.x >> 6;
    if (lane == 0) wsum[wid] = v;
    __syncthreads();
    if (threadIdx.x == 0) {
        float t = 0.f;
        for (int w = 0; w < BLK / 64; ++w) t += wsum[w];
        atomicAdd(out, t * (1.f / (float)(BATCH * NPTS)));
    }
}

extern "C" void kernel_launch(void* const* d_in, const int* in_sizes, int n_in,
                              void* d_out, int out_size, void* d_ws, size_t ws_size,
                              hipStream_t stream) {
    const float* p1 = (const float*)d_in[0];
    const float* p2 = (const float*)d_in[1];
    float* out = (float*)d_out;

    if (ws_size >= (size_t)TOTQ * sizeof(unsigned)) {
        unsigned* mins = (unsigned*)d_ws;
        init_kernel<<<TOTQ / BLK, BLK, 0, stream>>>(mins, out, TOTQ);
        cd_chunk_kernel<<<GRID, BLK, 0, stream>>>(p1, p2, mins);
        sum_kernel<<<64, BLK, 0, stream>>>(mins, out, TOTQ, 1.f / (float)(BATCH * NPTS));
    } else {
        zero_out_kernel<<<1, 1, 0, stream>>>(out);
        cd_full_kernel<<<128, BLK, 0, stream>>>(p1, p2, out);
    }
}